// Round 7
// baseline (130.937 us; speedup 1.0000x reference)
//
#include <hip/hip_runtime.h>

// Problem constants (fixed by setup_inputs in the reference).
#define BS   2
#define NT   2048
#define NH   8
#define WD   64
#define DEG  32

// ---------------------------------------------------------------------------
// R17: single fused kernel, no workspace, direct f32 gather.
// R2/R3/R6 A/Bs proved main-kernel time is invariant to pipeline depth,
// request count, and gathered line count -> the packed-f16 prepass (and its
// launch slot) is pure overhead IF gather traffic is free. This round removes
// the prepass entirely and gathers q/k/v as f32 straight from the inputs.
//
// One wave per (b, t, head-pair); combo = bid&7 XCD-pinned as before.
// Lane roles within each 32-lane half-wave (head hw = ln>>5):
//   jr = l>>2 (row group: neighbor rows j = 8i+jr, i=0..3)
//   m4 = l&3  (dim window: dims 16*m4 .. 16*m4+15)
// Phase 1: per-lane partial L1 over 16 dims x 4 rows; shfl_xor(1,2) sums the
// four m4 windows -> full logits, replicated across m4. Softmax is lane-local
// over 4 rows + shfl_xor(4,8,16) across jr -> p[i] lands exactly where
// phase 2 needs it (no broadcast shuffles at all).
// Phase 2: f32 fma over the same (row, dim-window) tile; shfl_xor(4,8,16)
// sums jr groups; lanes jr==0 store 4 float4s (contiguous 256 B per head).
// LDS = 128 B (coo only). All loads dwordx4.
// ---------------------------------------------------------------------------
__global__ __launch_bounds__(64) void l1attn_fused_f32(
    const float* __restrict__ q,
    const float* __restrict__ k,
    const float* __restrict__ v,
    const int* __restrict__ coo,
    float* __restrict__ out)
{
    const int bid   = blockIdx.x;
    const int combo = bid & 7;        // (b, head-pair) — XCD-pinned
    const int hp    = combo & 3;
    const int b     = combo >> 2;
    const int t     = bid >> 3;       // 0..2047
    const int ln    = threadIdx.x;    // 0..63
    const int hw    = ln >> 5;        // head-in-pair 0..1
    const int l     = ln & 31;        // lane in half-wave
    const int jr    = l >> 2;         // row group 0..7
    const int m4    = l & 3;          // dim window 0..3

    __shared__ int s_src[DEG];

    if (ln < DEG) {
        // coo row layout: [dst, src, sm]; rows t*DEG.. belong to dst=t.
        s_src[ln] = coo[(t * DEG + ln) * 3 + 1];
    }
    __syncthreads();   // single wave: compiles to waitcnt only

    const int h = hp * 2 + hw;
    const size_t tok = (size_t)NH * WD;              // 512 floats per token
    const float* qb = q + ((size_t)(b * NT + t) * NH + h) * WD + m4 * 16;
    const float* kb = k + (size_t)b * NT * tok + (size_t)h * WD + m4 * 16;
    const float* vb = v + (size_t)b * NT * tok + (size_t)h * WD + m4 * 16;

    int src[4];
    #pragma unroll
    for (int i = 0; i < 4; ++i) src[i] = s_src[8 * i + jr];

    // ---- loads: q (4), k (16), v (16) — all dwordx4, issued up front ----
    float4 qv[4];
    #pragma unroll
    for (int u = 0; u < 4; ++u) qv[u] = *(const float4*)(qb + 4 * u);

    float4 kv[4][4];
    #pragma unroll
    for (int i = 0; i < 4; ++i) {
        const float* kr = kb + (size_t)src[i] * tok;
        #pragma unroll
        for (int u = 0; u < 4; ++u) kv[i][u] = *(const float4*)(kr + 4 * u);
    }
    float4 vv[4][4];
    #pragma unroll
    for (int i = 0; i < 4; ++i) {
        const float* vr = vb + (size_t)src[i] * tok;
        #pragma unroll
        for (int u = 0; u < 4; ++u) vv[i][u] = *(const float4*)(vr + 4 * u);
    }

    // ---- phase 1: partial L1 (16 dims) per row, m4-reduce -> full logits ----
    float lg[4];
    #pragma unroll
    for (int i = 0; i < 4; ++i) {
        float a = 0.f;
        #pragma unroll
        for (int u = 0; u < 4; ++u) {
            a += fabsf(qv[u].x - kv[i][u].x);
            a += fabsf(qv[u].y - kv[i][u].y);
            a += fabsf(qv[u].z - kv[i][u].z);
            a += fabsf(qv[u].w - kv[i][u].w);
        }
        a += __shfl_xor(a, 1);         // sum the 4 m4 windows
        a += __shfl_xor(a, 2);
        lg[i] = -0.125f * a;           // scale = -1/sqrt(64)
    }

    // ---- softmax over 32 rows: local(4) + jr-reduce (xor 4,8,16) ----
    float mx = fmaxf(fmaxf(lg[0], lg[1]), fmaxf(lg[2], lg[3]));
    #pragma unroll
    for (int d = 4; d <= 16; d <<= 1) mx = fmaxf(mx, __shfl_xor(mx, d));
    float e[4];
    float S = 0.f;
    #pragma unroll
    for (int i = 0; i < 4; ++i) { e[i] = __expf(lg[i] - mx); S += e[i]; }
    #pragma unroll
    for (int d = 4; d <= 16; d <<= 1) S += __shfl_xor(S, d);
    // 33rd slot is -1e32 -> exp underflows to exactly 0; denominator unchanged.
    const float inv = 1.0f / S;
    float p[4];
    #pragma unroll
    for (int i = 0; i < 4; ++i) p[i] = e[i] * inv;

    // ---- phase 2: out[16 dims] = sum_i p[i] * v[row i] ----
    float o[16];
    #pragma unroll
    for (int z = 0; z < 16; ++z) o[z] = 0.f;
    #pragma unroll
    for (int i = 0; i < 4; ++i) {
        #pragma unroll
        for (int u = 0; u < 4; ++u) {
            o[4 * u + 0] = fmaf(p[i], vv[i][u].x, o[4 * u + 0]);
            o[4 * u + 1] = fmaf(p[i], vv[i][u].y, o[4 * u + 1]);
            o[4 * u + 2] = fmaf(p[i], vv[i][u].z, o[4 * u + 2]);
            o[4 * u + 3] = fmaf(p[i], vv[i][u].w, o[4 * u + 3]);
        }
    }
    // reduce over the 8 jr groups (xor 4, 8, 16 — stays in the half-wave)
    #pragma unroll
    for (int d = 4; d <= 16; d <<= 1) {
        #pragma unroll
        for (int z = 0; z < 16; ++z) o[z] += __shfl_xor(o[z], d);
    }

    if (jr == 0) {
        float* ob = out + ((size_t)(b * NT + t) * NH + h) * WD + 16 * m4;
        *(float4*)(ob)      = make_float4(o[0],  o[1],  o[2],  o[3]);
        *(float4*)(ob + 4)  = make_float4(o[4],  o[5],  o[6],  o[7]);
        *(float4*)(ob + 8)  = make_float4(o[8],  o[9],  o[10], o[11]);
        *(float4*)(ob + 12) = make_float4(o[12], o[13], o[14], o[15]);
    }
}

extern "C" void kernel_launch(void* const* d_in, const int* in_sizes, int n_in,
                              void* d_out, int out_size, void* d_ws, size_t ws_size,
                              hipStream_t stream) {
    const float* q   = (const float*)d_in[0];
    const float* k   = (const float*)d_in[1];
    const float* v   = (const float*)d_in[2];
    const int*   coo = (const int*)d_in[3];
    float*       o   = (float*)d_out;

    (void)d_ws; (void)ws_size;   // R17: workspace unused (no prepass)
    hipLaunchKernelGGL(l1attn_fused_f32, dim3(BS * NT * 4), dim3(64), 0,
                       stream, q, k, v, coo, o);
}

// Round 8
// 98.421 us; speedup vs baseline: 1.3304x; 1.3304x over previous
//
#include <hip/hip_runtime.h>

// Problem constants (fixed by setup_inputs in the reference).
#define BS   2
#define NT   2048
#define NH   8
#define WD   64
#define DEG  32

#define PK_ROWS   (BS * 4 * NT)        // (b, head-pair, src) rows
#define PK_ROW_B  512                  // 256B k(2 heads f16) + 256B v(2 heads f16)
#define PK_UINTS  (PK_ROWS * (PK_ROW_B / 4))   // 2,097,152 uints = 8 MB

typedef _Float16 half2_t __attribute__((ext_vector_type(2)));

#if defined(__has_builtin)
#if __has_builtin(__builtin_amdgcn_fdot2)
#define HAVE_FDOT2 1
#endif
#endif

__device__ __forceinline__ unsigned short f2h(float f) {
    _Float16 h = (_Float16)f;          // RNE
    unsigned short u; __builtin_memcpy(&u, &h, 2); return u;
}
__device__ __forceinline__ half2_t u2h2(unsigned int w) {
    half2_t r; __builtin_memcpy(&r, &w, 4); return r;
}
__device__ __forceinline__ unsigned int h22u(half2_t h) {
    unsigned int u; __builtin_memcpy(&u, &h, 4); return u;
}
__device__ __forceinline__ half2_t habs2(half2_t x) {
    unsigned int u = h22u(x) & 0x7fff7fffu;
    return u2h2(u);
}

// ---------------------------------------------------------------------------
// Prepass: pack k and v into fused f16 rows in d_ws (verbatim R1, verified).
// Row r = ((b*4 + hp)*NT + s), 512 B: [k heads hp*2,hp*2+1 | v same] as f16.
// ---------------------------------------------------------------------------
__global__ __launch_bounds__(256) void pack_kv_f16(
    const float* __restrict__ k,
    const float* __restrict__ v,
    unsigned int* __restrict__ packed)
{
    const int u    = blockIdx.x * 256 + threadIdx.x;  // 0 .. PK_UINTS-1 exact
    const int row  = u >> 7;          // 128 uints per row
    const int pos  = u & 127;
    const int part = pos >> 6;        // 0 = k, 1 = v
    const int e    = pos & 63;        // uint within part (2 f16 elems)
    const int s    = row & (NT - 1);
    const int hp   = (row >> 11) & 3;
    const int b    = row >> 13;
    const int elem = e * 2;
    const int h_in = elem >> 6;       // head-in-pair
    const int w0   = elem & 63;       // width

    const float* src = (part == 0 ? k : v)
        + (((size_t)(b * NT + s) * NH + hp * 2 + h_in) << 6) + w0;
    float2 f = *(const float2*)src;
    packed[u] = (unsigned int)f2h(f.x) | ((unsigned int)f2h(f.y) << 16);
}

// ---------------------------------------------------------------------------
// Main (R18): 4-wave blocks (256 thr), one t per wave, ZERO LDS, all-register.
// R7 counters: VALUBusy 11%, hbm 4.5%, conflicts 0, Occupancy 57% -> the
// limiter is the ~16 workgroups/CU dispatch cap on 1-wave blocks (half the
// wave slots unusable). 4-wave blocks + 0 LDS + ~60 VGPR -> 28-32 waves/CU.
// Lane roles per half-wave (head hw = ln>>5), from the verified R7 mapping:
//   jr = l>>2 (row group: rows j = 8i+jr), m4 = l&3 (dims 16m4..16m4+15).
// coo is read per-lane (4-lane-uniform addresses, 96 KB hot region) -- no
// staging, no __syncthreads anywhere. k/v gathered from packed f16 rows as
// 2 x uint4 per row-segment; v issued AFTER phase 1 to cap live VGPRs.
// Softmax: lane-local over 4 rows + shfl_xor(4,8,16); no broadcasts needed.
// ---------------------------------------------------------------------------
__global__ __launch_bounds__(256) void l1attn_gather4(
    const float* __restrict__ q,
    const unsigned int* __restrict__ packed,
    const int* __restrict__ coo,
    float* __restrict__ out)
{
    const int bid   = blockIdx.x;
    const int combo = bid & 7;        // (b, head-pair) — XCD-pinned
    const int hp    = combo & 3;
    const int b     = combo >> 2;
    const int wid   = threadIdx.x >> 6;          // wave 0..3
    const int t     = (bid >> 3) * 4 + wid;      // 0..2047
    const int ln    = threadIdx.x & 63;
    const int hw    = ln >> 5;        // head-in-pair 0..1
    const int l     = ln & 31;        // lane in half-wave
    const int jr    = l >> 2;         // row group 0..7
    const int m4    = l & 3;          // dim window 0..3

    // ---- per-lane coo gather (rows 8i+jr of this t's 32-row block) ----
    int src[4];
    #pragma unroll
    for (int i = 0; i < 4; ++i)
        src[i] = coo[(t * DEG + 8 * i + jr) * 3 + 1];

    // packed-row base for this (b,hp) + this lane's (head, dim-window) slice
    const char* pb = (const char*)packed
                   + (size_t)((b * 4 + hp) * NT) * PK_ROW_B
                   + hw * 128 + m4 * 32;

    // ---- k loads: 4 rows x 2 uint4 (32 B = 16 f16 dims per row) ----
    uint4 kk[4][2];
    #pragma unroll
    for (int i = 0; i < 4; ++i) {
        const char* kr = pb + (size_t)src[i] * PK_ROW_B;
        kk[i][0] = *(const uint4*)(kr);
        kk[i][1] = *(const uint4*)(kr + 16);
    }

    // ---- q: 16 dims f32 -> 8 f16x2 words ----
    unsigned int qh[8];
    {
        const float* qb = q + ((size_t)(b * NT + t) * NH + hp * 2 + hw) * WD
                        + m4 * 16;
        #pragma unroll
        for (int u = 0; u < 8; ++u) {
            float2 f = *(const float2*)(qb + 2 * u);
            qh[u] = (unsigned int)f2h(f.x) | ((unsigned int)f2h(f.y) << 16);
        }
    }

    // ---- phase 1: partial L1 (16 dims) per row, m4-reduce -> full logits ----
#ifdef HAVE_FDOT2
    const half2_t one2 = {(_Float16)1.0f, (_Float16)1.0f};
#endif
    float lg[4];
    #pragma unroll
    for (int i = 0; i < 4; ++i) {
        float a = 0.f;
        const unsigned int* kw = (const unsigned int*)&kk[i][0];  // 8 words
        #pragma unroll
        for (int u = 0; u < 8; ++u) {
            half2_t kh = u2h2(kw[u]);
            half2_t qv = u2h2(qh[u]);
            half2_t ad = habs2(qv - kh);
#ifdef HAVE_FDOT2
            a = __builtin_amdgcn_fdot2(ad, one2, a, false);  // f32 accum
#else
            a += (float)ad.x + (float)ad.y;
#endif
        }
        a += __shfl_xor(a, 1);         // sum the 4 m4 windows
        a += __shfl_xor(a, 2);
        lg[i] = -0.125f * a;           // scale = -1/sqrt(64)
    }

    // ---- v loads (issued after phase 1 to cap live VGPRs) ----
    uint4 vv[4][2];
    #pragma unroll
    for (int i = 0; i < 4; ++i) {
        const char* vr = pb + 256 + (size_t)src[i] * PK_ROW_B;
        vv[i][0] = *(const uint4*)(vr);
        vv[i][1] = *(const uint4*)(vr + 16);
    }

    // ---- softmax over 32 rows: local(4) + jr-reduce (xor 4,8,16) ----
    float mx = fmaxf(fmaxf(lg[0], lg[1]), fmaxf(lg[2], lg[3]));
    #pragma unroll
    for (int d = 4; d <= 16; d <<= 1) mx = fmaxf(mx, __shfl_xor(mx, d));
    float e[4];
    float S = 0.f;
    #pragma unroll
    for (int i = 0; i < 4; ++i) { e[i] = __expf(lg[i] - mx); S += e[i]; }
    #pragma unroll
    for (int d = 4; d <= 16; d <<= 1) S += __shfl_xor(S, d);
    // 33rd slot is -1e32 -> exp underflows to exactly 0; denominator unchanged.
    const float inv = 1.0f / S;

    // ---- phase 2 (f16 packed fma): o[u] covers dims 16m4+2u, +1 ----
    half2_t o[8];
    #pragma unroll
    for (int u = 0; u < 8; ++u) o[u] = half2_t{(_Float16)0.0f, (_Float16)0.0f};
    #pragma unroll
    for (int i = 0; i < 4; ++i) {
        const _Float16 ph = (_Float16)(e[i] * inv);
        const half2_t p2 = {ph, ph};
        const unsigned int* vw = (const unsigned int*)&vv[i][0];  // 8 words
        #pragma unroll
        for (int u = 0; u < 8; ++u)
            o[u] = __builtin_elementwise_fma(p2, u2h2(vw[u]), o[u]);
    }
    // reduce over the 8 jr groups (xor 4, 8, 16 — stays in the half-wave)
    #pragma unroll
    for (int d = 4; d <= 16; d <<= 1) {
        #pragma unroll
        for (int u = 0; u < 8; ++u) {
            unsigned int w = (unsigned int)__shfl_xor((int)h22u(o[u]), d);
            o[u] = o[u] + u2h2(w);
        }
    }

    if (jr == 0) {
        float* ob = out + ((size_t)(b * NT + t) * NH + hp * 2 + hw) * WD
                  + 16 * m4;
        *(float4*)(ob)      = make_float4((float)o[0].x, (float)o[0].y,
                                          (float)o[1].x, (float)o[1].y);
        *(float4*)(ob + 4)  = make_float4((float)o[2].x, (float)o[2].y,
                                          (float)o[3].x, (float)o[3].y);
        *(float4*)(ob + 8)  = make_float4((float)o[4].x, (float)o[4].y,
                                          (float)o[5].x, (float)o[5].y);
        *(float4*)(ob + 12) = make_float4((float)o[6].x, (float)o[6].y,
                                          (float)o[7].x, (float)o[7].y);
    }
}

// ---------------------------------------------------------------------------
// Fallback (ws too small): round-6 fp32 kernel, unchanged.
// ---------------------------------------------------------------------------
__global__ __launch_bounds__(64) void l1attn_sparse_fp32(
    const float* __restrict__ q,
    const float* __restrict__ k,
    const float* __restrict__ v,
    const int* __restrict__ coo,
    float* __restrict__ out)
{
    const int bid   = blockIdx.x;
    const int combo = bid & 7;
    const int hp    = combo & 3;
    const int b     = combo >> 2;
    const int t     = bid >> 3;
    const int ln    = threadIdx.x;
    const int hw    = ln >> 5;
    const int l     = ln & 31;

    __shared__ int   s_src[DEG];
    __shared__ float s_q[2 * WD];
    __shared__ float s_k[DEG * 2 * WD];

    if (ln < DEG) s_src[ln] = coo[(t * DEG + ln) * 3 + 1];
    {
        const float2* qrow = (const float2*)
            (q + ((size_t)(b * NT + t) * NH + hp * 2) * WD);
        float2 qv = qrow[ln];
        s_q[2 * ln] = qv.x; s_q[2 * ln + 1] = qv.y;
    }
    __syncthreads();
    {
        #pragma unroll
        for (int r = 0; r < 16; ++r) {
            const int j = 2 * r + hw;
            const int s = s_src[j];
            const int chunk = (l + j) & 31;
            const float* gaddr = k + ((size_t)(b * NT + s) * NH + hp * 2) * WD
                               + chunk * 4;
            float* laddr = s_k + 2 * r * (2 * WD);
            __builtin_amdgcn_global_load_lds(
                (const __attribute__((address_space(1))) void*)gaddr,
                (__attribute__((address_space(3))) void*)laddr, 16, 0, 0);
        }
    }
    const int h  = hp * 2 + hw;
    const int jg = l >> 4;
    const int wq = l & 15;
    float4 vr[16];
    #pragma unroll
    for (int i = 0; i < 16; ++i) {
        const int sv = s_src[2 * i + jg];
        vr[i] = *(const float4*)(v + ((size_t)(b * NT + sv) * NH + h) * WD + 4 * wq);
    }
    __syncthreads();
    const float* qh = s_q + hw * WD;
    float acc = 0.f;
    #pragma unroll
    for (int i = 0; i < 16; ++i) {
        const int slot = ((hw * 16 + i) - l) & 31;
        float4 kv = *(const float4*)(s_k + l * (2 * WD) + slot * 4);
        const int wb = i * 4;
        acc += fabsf(qh[wb] - kv.x) + fabsf(qh[wb + 1] - kv.y)
             + fabsf(qh[wb + 2] - kv.z) + fabsf(qh[wb + 3] - kv.w);
    }
    float logit = -0.125f * acc;
    float m = logit;
    #pragma unroll
    for (int d = 16; d >= 1; d >>= 1) m = fmaxf(m, __shfl_xor(m, d));
    float e = __expf(logit - m);
    float ssum = e;
    #pragma unroll
    for (int d = 16; d >= 1; d >>= 1) ssum += __shfl_xor(ssum, d);
    const float p = e / ssum;
    float4 o4 = make_float4(0.f, 0.f, 0.f, 0.f);
    #pragma unroll
    for (int i = 0; i < 16; ++i) {
        const float pj = __shfl(p, 2 * i + jg, 32);
        o4.x += pj * vr[i].x; o4.y += pj * vr[i].y;
        o4.z += pj * vr[i].z; o4.w += pj * vr[i].w;
    }
    o4.x += __shfl_xor(o4.x, 16); o4.y += __shfl_xor(o4.y, 16);
    o4.z += __shfl_xor(o4.z, 16); o4.w += __shfl_xor(o4.w, 16);
    if (jg == 0)
        *(float4*)(out + ((size_t)(b * NT + t) * NH + h) * WD + 4 * wq) = o4;
}

extern "C" void kernel_launch(void* const* d_in, const int* in_sizes, int n_in,
                              void* d_out, int out_size, void* d_ws, size_t ws_size,
                              hipStream_t stream) {
    const float* q   = (const float*)d_in[0];
    const float* k   = (const float*)d_in[1];
    const float* v   = (const float*)d_in[2];
    const int*   coo = (const int*)d_in[3];
    float*       o   = (float*)d_out;

    if (ws_size >= (size_t)PK_UINTS * 4) {
        unsigned int* packed = (unsigned int*)d_ws;
        hipLaunchKernelGGL(pack_kv_f16, dim3(PK_UINTS / 256), dim3(256), 0,
                           stream, k, v, packed);
        // 4 t's per block (one per wave): 16384/4 = 4096 blocks of 256.
        hipLaunchKernelGGL(l1attn_gather4, dim3(BS * NT), dim3(256), 0,
                           stream, q, packed, coo, o);
    } else {
        hipLaunchKernelGGL(l1attn_sparse_fp32, dim3(BS * NT * 4), dim3(64), 0,
                           stream, q, k, v, coo, o);
    }
}